// Round 16
// baseline (1742.146 us; speedup 1.0000x reference)
//
#include <hip/hip_runtime.h>
#include <hip/hip_bf16.h>
#include <stdint.h>

#define B_    64
#define T_    512
#define NIN_  64
#define N_    1024
#define NOUT_ 32

// persistent-scan decomposition (R2/R11..R15 geometry, verbatim)
#define NISL  16
#define BPI   16
#define MB    4
#define COLS  64
#define NT    4
#define KW    256
#define KT    8

#define MAIL_WORDS (NISL * BPI * BPI)           // R12/R13/R15-proven mailbox
#define EX_WORDS   (2 * B_ * (N_ / 2))          // two parity buffers

typedef float f32x4 __attribute__((ext_vector_type(4)));
typedef short s16x8 __attribute__((ext_vector_type(8)));

__device__ __forceinline__ unsigned short f2bf(float f) {
  union { float f; unsigned u; } v; v.f = f;
  unsigned r = v.u + 0x7FFFu + ((v.u >> 16) & 1u);
  return (unsigned short)(r >> 16);
}

__device__ __forceinline__ s16x8 cvt8(float4 a, float4 b) {
  s16x8 f;
  f[0] = (short)f2bf(a.x); f[1] = (short)f2bf(a.y);
  f[2] = (short)f2bf(a.z); f[3] = (short)f2bf(a.w);
  f[4] = (short)f2bf(b.x); f[5] = (short)f2bf(b.y);
  f[6] = (short)f2bf(b.z); f[7] = (short)f2bf(b.w);
  return f;
}

// R7/R13/R15-proven exchange loads (coherence-point fresh)
#define LD16S(dst, base, OFF) \
  asm volatile("global_load_dwordx4 %0, %1, off offset:" #OFF " sc0 sc1" \
               : "=v"(dst) : "v"(base) : "memory")
#define LDALLS(bpv) do { \
  LD16S(afr[0], bpv, 0);   LD16S(afr[1], bpv, 64);  \
  LD16S(afr[2], bpv, 128); LD16S(afr[3], bpv, 192); \
  LD16S(afr[4], bpv, 256); LD16S(afr[5], bpv, 320); \
  LD16S(afr[6], bpv, 384); LD16S(afr[7], bpv, 448); } while (0)
// R4/R6/R7-proven dword-granular step-tag check (bit 0 of every dword)
#define TAGCHECK(okvar) do { \
  unsigned bad_ = 0; \
  _Pragma("unroll") \
  for (int kt_ = 0; kt_ < KT; ++kt_) { \
    union { s16x8 v; unsigned u[4]; } w_; w_.v = afr[kt_]; \
    bad_ |= (w_.u[0] ^ tgm) | (w_.u[1] ^ tgm) | (w_.u[2] ^ tgm) | (w_.u[3] ^ tgm); \
  } \
  okvar = __all((int)((bad_ & 1u) == 0u)); \
} while (0)

// ---------------------------------------------------------------------------
// R15 + tagged speculative tail load:
//  * tail(t): issue next step's 8 exchange loads FIRST (after the post), then
//    aux (X/R stores, SN/RN/U prefetch). By head(t+1) the spec RT is resolved.
//  * head(t): counted vmcnt retires exactly the spec loads (in-order retire;
//    aux HBM ops stay in flight); bit-0 tags validate. Hit: skip poll+reload.
//    Miss: R15's exact poll -> reload -> vmcnt(0).
//  * The poll is NEVER removed: on hit it becomes the PUBLISH GATE (flag load
//    pre-issued before MFMA, checked after reduce) — preserving the overwrite
//    invariant: no peer can publish r_{t+2} into buf[t&1] until our slot
//    >= t+2, posted only after our gate passed. Spec reads therefore see only
//    {stale t-2, fresh t}, which tags distinguish.
// ---------------------------------------------------------------------------
__global__ __launch_bounds__(256, 1) void rnn_scan(
    const float* __restrict__ U, const float* __restrict__ X0,
    const float* __restrict__ SN, const float* __restrict__ RN,
    const float* __restrict__ Wi, const float* __restrict__ Bi,
    const float* __restrict__ Wr,
    float* __restrict__ X, float* __restrict__ R,
    unsigned* __restrict__ mail, unsigned* __restrict__ ex)
{
  const int bid   = blockIdx.x;
  const int isl   = bid / BPI, slice = bid % BPI;
  const int tid   = threadIdx.x;
  const int wave  = tid >> 6, lane = tid & 63;
  const int l15   = lane & 15, koct = lane >> 4;
  const int colbase = slice * COLS;

  s16x8 bfrag[KT][NT];
#pragma unroll
  for (int kt = 0; kt < KT; ++kt) {
    const int k0 = wave * KW + kt * 32 + koct * 8;
#pragma unroll
    for (int nt = 0; nt < NT; ++nt) {
      const float4* q = (const float4*)(Wr + (size_t)(colbase + nt * 16 + l15) * N_ + k0);
      bfrag[kt][nt] = cvt8(q[0], q[1]);
    }
  }
  s16x8 wifrag[NT];
  if (wave < 2) {
#pragma unroll
    for (int nt = 0; nt < NT; ++nt) {
      const float4* q = (const float4*)(Wi + (size_t)(colbase + nt * 16 + l15) * NIN_ + wave * 32 + koct * 8);
      wifrag[nt] = cvt8(q[0], q[1]);
    }
  }

  const int cc   = lane;
  const int bloc = wave;
  const int bg   = isl * MB + bloc;
  const int nn   = colbase + cc;
  const int abatch = isl * MB + (l15 & 3);

  float x = X0[nn];
  const float bin = Bi[nn];
  const float r0 = fmaxf(tanhf(x), 0.f);

  const float* SNp = SN + (size_t)bg * T_ * N_ + nn;
  const float* RNp = RN + (size_t)bg * T_ * N_ + nn;
  float*       Xp  = X  + (size_t)bg * T_ * N_ + nn;
  float*       Rp  = R  + (size_t)bg * T_ * N_ + nn;
  const float* Up  = U  + (size_t)(isl * MB + (l15 & 3)) * T_ * NIN_ + wave * 32 + koct * 8;

  __shared__ float part[4][COLS][MB];

  const unsigned* const myline = mail + (isl * BPI + slice) * BPI;
  unsigned* const postcol      = mail + isl * BPI * BPI + slice;

  const int kofs = (wave * KW + koct * 8) >> 1;
  const unsigned* const exb0 = ex + (size_t)abatch * (N_ / 2) + kofs;         // parity 0
  const unsigned* const exb1 = exb0 + (size_t)B_ * (N_ / 2);                  // parity 1
  unsigned* const exw0 = ex + (size_t)bg * (N_ / 2) + (nn >> 1);
  unsigned* const exw1 = exw0 + (size_t)B_ * (N_ / 2);

  // prologue aux prefetch for t=0 (drained by the prologue barrier)
  float sn_c = SNp[0], rn_c = RNp[0];
  float4 uc0{}, uc1{};
  if (wave < 2) { const float4* q = (const float4*)Up; uc0 = q[0]; uc1 = q[1]; }

  // publish r_0 (tag 0) -> B_drain -> post -> spec load for t=0 -> drain
  {
    unsigned short h = f2bf(r0);
    unsigned other = __shfl_xor((unsigned)h, 1);
    unsigned vv  = ((unsigned)h & ~1u) | (other << 16);      // tag bit = 0
    unsigned vv2 = __shfl_xor(vv, 2);
    if ((lane & 3) == 0) {
      uint64_t q8 = (uint64_t)vv | ((uint64_t)vv2 << 32);
      __hip_atomic_store((uint64_t*)exw0, q8, __ATOMIC_RELAXED, __HIP_MEMORY_SCOPE_AGENT);
    }
  }
  __syncthreads();
  if (tid < BPI)
    __hip_atomic_store(postcol + tid * BPI, 1u, __ATOMIC_RELAXED, __HIP_MEMORY_SCOPE_AGENT);

  s16x8 afr[KT];                 // persists across the tail/head boundary
  LDALLS(exb0);                  // speculative load for t=0
  asm volatile("s_waitcnt vmcnt(0)" ::: "memory");
  __builtin_amdgcn_sched_barrier(0);

  for (int t = 0; t < T_; ++t) {
    const unsigned tgm = ((t >> 1) & 1) ? 0xFFFFFFFFu : 0u;
    const unsigned need = (unsigned)(t + 1);

    // ---- 1. head wait: retire exactly the 8 spec loads (in-order vmcnt);
    //         aux HBM ops from the tail stay in flight ----
    if (wave < 2) asm volatile("s_waitcnt vmcnt(5)" ::: "memory");
    else          asm volatile("s_waitcnt vmcnt(4)" ::: "memory");
    __builtin_amdgcn_sched_barrier(0);
    int ok; TAGCHECK(ok);

    // ---- 2. pre-issue the gate-flag load (latency hides under MFMA) ----
    unsigned fv0 = __hip_atomic_load(myline + l15, __ATOMIC_RELAXED,
                                     __HIP_MEMORY_SCOPE_AGENT);
    if (!ok) {
      // miss: full poll (R15-proven), then single reload (drain-before-post
      // guarantees freshness after flags -- R13/R15 invariant)
      if (!__all((int)(fv0 >= need))) {
        for (;;) {
          unsigned fv = __hip_atomic_load(myline + l15, __ATOMIC_RELAXED,
                                          __HIP_MEMORY_SCOPE_AGENT);
          if (__all((int)(fv >= need))) break;
          __builtin_amdgcn_s_sleep(1);
        }
      }
      const unsigned* bp = (t & 1) ? exb1 : exb0;
      LDALLS(bp);
      asm volatile("s_waitcnt vmcnt(0)" ::: "memory");
      __builtin_amdgcn_sched_barrier(0);
    }

    // ---- 3. MFMA ----
    f32x4 acc[NT];
#pragma unroll
    for (int nt = 0; nt < NT; ++nt) acc[nt] = f32x4{0.f, 0.f, 0.f, 0.f};
#pragma unroll
    for (int kt = 0; kt < KT; ++kt)
#pragma unroll
      for (int nt = 0; nt < NT; ++nt)
        acc[nt] = __builtin_amdgcn_mfma_f32_16x16x32_bf16(afr[kt], bfrag[kt][nt], acc[nt], 0, 0, 0);
    if (wave < 2) {
      s16x8 ua = cvt8(uc0, uc1);
#pragma unroll
      for (int nt = 0; nt < NT; ++nt)
        acc[nt] = __builtin_amdgcn_mfma_f32_16x16x32_bf16(ua, wifrag[nt], acc[nt], 0, 0, 0);
    }

    // ---- 4. cross-wave K-partials (R4-proven swizzle) + state update ----
    if (lane < 16) {
#pragma unroll
      for (int nt = 0; nt < NT; ++nt) {
        const int s = (nt * 2 + (lane >> 3)) & 3;
        f32x4 a = acc[nt];
        if (s & 1) a = f32x4{a[1], a[0], a[3], a[2]};
        if (s & 2) a = f32x4{a[2], a[3], a[0], a[1]};
        *(f32x4*)&part[wave][nt * 16 + lane][0] = a;
      }
    }
    __syncthreads();                                   // B_part
    const int sr = (cc >> 3) & 3;
    const float mat = part[0][cc][bloc ^ sr] + part[1][cc][bloc ^ sr] +
                      part[2][cc][bloc ^ sr] + part[3][cc][bloc ^ sr];
    const float xn = x + 0.1f * (-x + mat + bin + sn_c);
    const float rv = fmaxf(tanhf(xn), 0.f) + rn_c;
    x = xn;

    // ---- 5. publish GATE (hit path): the poll is never removed, it just
    //         moved after compute; stragglers find fv0 pre-satisfied ----
    if (ok) {
      if (!__all((int)(fv0 >= need))) {
        for (;;) {
          unsigned fv = __hip_atomic_load(myline + l15, __ATOMIC_RELAXED,
                                          __HIP_MEMORY_SCOPE_AGENT);
          if (__all((int)(fv >= need))) break;
          __builtin_amdgcn_s_sleep(1);
        }
      }
    }

    // ---- 6. publish r_{t+1} (tagged) -> B_drain -> post ----
    {
      const unsigned tgn = ((t + 1) >> 1) & 1;
      unsigned short h = f2bf(rv);
      unsigned other = __shfl_xor((unsigned)h, 1);
      unsigned vv  = (((unsigned)h & ~1u) | tgn) | (other << 16);
      unsigned vv2 = __shfl_xor(vv, 2);
      if ((lane & 3) == 0) {
        uint64_t q8 = (uint64_t)vv | ((uint64_t)vv2 << 32);
        __hip_atomic_store((uint64_t*)((t & 1) ? exw0 : exw1), q8,
                           __ATOMIC_RELAXED, __HIP_MEMORY_SCOPE_AGENT);
      }
    }
    __syncthreads();                                   // B_drain (data<flag)
    if (tid < BPI)
      __hip_atomic_store(postcol + tid * BPI, (unsigned)(t + 2),
                         __ATOMIC_RELAXED, __HIP_MEMORY_SCOPE_AGENT);

    // ---- 7. TAIL: spec loads FIRST (head's counted wait targets them),
    //         then aux (X/R stores + SN/RN/U prefetch for t+1) ----
    if (t + 1 < T_) {
      const unsigned* bpn = ((t + 1) & 1) ? exb1 : exb0;
      LDALLS(bpn);
    }
    Xp[(size_t)t * N_] = xn;
    Rp[(size_t)t * N_] = rv;
    if (t + 1 < T_) {
      sn_c = SNp[(size_t)(t + 1) * N_];
      rn_c = RNp[(size_t)(t + 1) * N_];
      if (wave < 2) {
        const float4* q = (const float4*)(Up + (size_t)(t + 1) * NIN_);
        uc0 = q[0]; uc1 = q[1];
      }
    }
  }
}

// ---------------------------------------------------------------------------
// zout — R15 verbatim (proven).
// ---------------------------------------------------------------------------
#define TCH 64
__global__ __launch_bounds__(256, 2) void rnn_zout(
    const float* __restrict__ Rm, const float* __restrict__ ON,
    const float* __restrict__ Wo, const float* __restrict__ Bo,
    float* __restrict__ Z)
{
  const int bid = blockIdx.x;
  const int b = bid >> 3, tq = bid & 7;
  const int tid = threadIdx.x;
  const int o = tid & 31, kc = tid >> 5;

  float4 wv[32];
  const float4* wp = (const float4*)(Wo + (size_t)o * N_ + kc * 128);
#pragma unroll
  for (int i = 0; i < 32; ++i) wv[i] = wp[i];
  const float bo = Bo[o];

  __shared__ float Rl[2][N_];
  __shared__ float zred[2][8][32];

  const int t0 = tq * TCH;
  ((float4*)Rl[0])[tid] = ((const float4*)(Rm + ((size_t)b * T_ + t0) * N_))[tid];
  __syncthreads();

  for (int i = 0; i < TCH; ++i) {
    const int cur = i & 1;
    const size_t row = (size_t)b * T_ + t0 + i;
    float4 nx;
    if (i + 1 < TCH)
      nx = ((const float4*)(Rm + (row + 1) * N_))[tid];
    float a0 = 0.f;
#pragma unroll
    for (int j = 0; j < 32; ++j) {
      const float* rp = &Rl[cur][kc * 128 + j * 4];
      a0 += wv[j].x * rp[0] + wv[j].y * rp[1] + wv[j].z * rp[2] + wv[j].w * rp[3];
    }
    if (i + 1 < TCH)
      ((float4*)Rl[cur ^ 1])[tid] = nx;
    zred[cur][kc][o] = a0;
    __syncthreads();
    if (tid < 32) {
      float z = bo;
#pragma unroll
      for (int k = 0; k < 8; ++k) z += zred[cur][k][tid];
      Z[row * NOUT_ + tid] = z + ON[row * NOUT_ + tid];
    }
  }
}

extern "C" void kernel_launch(void* const* d_in, const int* in_sizes, int n_in,
                              void* d_out, int out_size, void* d_ws, size_t ws_size,
                              hipStream_t stream) {
  const float* U  = (const float*)d_in[0];
  const float* X0 = (const float*)d_in[1];
  const float* SN = (const float*)d_in[2];
  const float* RN = (const float*)d_in[3];
  const float* ON = (const float*)d_in[4];
  const float* Wi = (const float*)d_in[5];
  const float* Bi = (const float*)d_in[6];
  const float* Wr = (const float*)d_in[7];
  const float* Wo = (const float*)d_in[8];
  const float* Bo = (const float*)d_in[9];

  float* X = (float*)d_out;
  float* R = X + (size_t)B_ * T_ * N_;
  float* Z = R + (size_t)B_ * T_ * N_;

  unsigned* mail = (unsigned*)d_ws;                        // [NISL][16][16]
  unsigned* ex   = (unsigned*)((char*)d_ws + 65536);       // [2][B_][N_/2]

  // mail=0 (first need is 1); ex=0xFF (tag bit 1 => stale at t=0, kills
  // cross-replay staleness). Both graph-capture-safe.
  hipMemsetAsync(mail, 0, MAIL_WORDS * sizeof(unsigned), stream);
  hipMemsetAsync(ex, 0xFF, EX_WORDS * sizeof(unsigned), stream);

  hipLaunchKernelGGL(rnn_scan, dim3(NISL * BPI), dim3(256), 0, stream,
                     U, X0, SN, RN, Wi, Bi, Wr, X, R, mail, ex);
  hipLaunchKernelGGL(rnn_zout, dim3(B_ * (T_ / TCH)), dim3(256), 0, stream,
                     R, ON, Wo, Bo, Z);
}